// Round 1
// baseline (199.212 us; speedup 1.0000x reference)
//
#include <hip/hip_runtime.h>
#include <math.h>

// Problem constants
#define H28 28
#define G784 784
#define BATCH 32
#define NOFF 3025   // 55*55 lattice offsets (|di|,|dj| <= 27)
#define NKEY 1459   // keys di*di+dj*dj in [0, 1458]
#define TPTS 25
#define KMAX 2
#define NFEAT 50    // KMAX*TPTS
#define OUTF 50
#define NCLS 10

// ---------------------------------------------------------------------------
// Kernel 1: DTM. grid = (BATCH, 4), block = 256.
// Each block: builds the counting-sorted offset table in LDS (identical work,
// replicated), loads w[b] to LDS, computes bound, then each of 196 threads
// scans its pixel's sorted neighborhood with early exit.
// ---------------------------------------------------------------------------
__global__ __launch_bounds__(256) void dtm_kernel(const float* __restrict__ x,
                                                  float* __restrict__ v) {
  __shared__ int   hist[NKEY];     // histogram, then scatter cursor
  __shared__ unsigned int ofs_ij[NOFF]; // packed (di,dj) as two int16
  __shared__ float ofs_d2[NOFF];   // float32 (float32 dist)^2, matches SDIST**2
  __shared__ float w_s[G784];
  __shared__ float red[256];
  __shared__ int   seg[256];

  const int tid   = threadIdx.x;
  const int b     = blockIdx.x;
  const int chunk = blockIdx.y;    // 0..3, 196 pixels per chunk

  // --- 1. histogram of integer squared distances over all 3025 offsets ---
  for (int i = tid; i < NKEY; i += 256) hist[i] = 0;
  __syncthreads();
  for (int i = tid; i < NOFF; i += 256) {
    int di = i / 55 - 27, dj = i % 55 - 27;
    atomicAdd(&hist[di * di + dj * dj], 1);
  }
  __syncthreads();

  // --- 2. exclusive scan of hist (segmented + Hillis-Steele over 256) ---
  const int SEG = 6;               // 6*256 = 1536 >= 1459
  int base0 = tid * SEG;
  int s = 0;
  for (int k = 0; k < SEG; k++) { int idx = base0 + k; if (idx < NKEY) s += hist[idx]; }
  seg[tid] = s;
  __syncthreads();
  for (int off = 1; off < 256; off <<= 1) {
    int add = (tid >= off) ? seg[tid - off] : 0;
    __syncthreads();
    seg[tid] += add;
    __syncthreads();
  }
  int run = seg[tid] - s;          // exclusive prefix for this thread's segment
  for (int k = 0; k < SEG; k++) {
    int idx = base0 + k;
    if (idx < NKEY) { int h = hist[idx]; hist[idx] = run; run += h; }
  }
  __syncthreads();

  // --- 3. scatter offsets into sorted-by-key order ---
  for (int i = tid; i < NOFF; i += 256) {
    int di = i / 55 - 27, dj = i % 55 - 27;
    int key = di * di + dj * dj;
    int pos = atomicAdd(&hist[key], 1);
    ofs_ij[pos] = ((unsigned)(di & 0xffff)) | (((unsigned)(dj & 0xffff)) << 16);
    float sd = (float)(sqrt((double)key) * (224.0 / 27.0)); // == f32(SDIST)
    ofs_d2[pos] = sd * sd;                                  // == f32 SDIST**2
  }

  // --- 4. load w[b], block-reduce sum -> bound ---
  float ps = 0.f;
  for (int i = tid; i < G784; i += 256) {
    float wv = x[b * G784 + i];
    w_s[i] = wv;
    ps += wv;
  }
  red[tid] = ps;
  __syncthreads();
  for (int off = 128; off > 0; off >>= 1) {
    if (tid < off) red[tid] += red[tid + off];
    __syncthreads();
  }
  const float bound = 0.2f * red[0];

  // --- 5. per-pixel scan with early exit ---
  if (tid < 196) {
    int g  = chunk * 196 + tid;     // < 784
    int i1 = g / H28, j1 = g % H28;
    float cw = 0.f, cwd = 0.f, cwp = 0.f, cwdp = 0.f, dk2 = 0.f;
    for (int o = 0; o < NOFF; o++) {
      unsigned ij = ofs_ij[o];
      int di = (short)(ij & 0xffffu);
      int dj = (short)((ij >> 16) & 0xffffu);
      int i2 = i1 + di, j2 = j1 + dj;
      if ((unsigned)i2 < (unsigned)H28 && (unsigned)j2 < (unsigned)H28) {
        float wv = w_s[i2 * H28 + j2];
        float d2 = ofs_d2[o];
        float ncw = __fadd_rn(cw, wv);
        if (ncw >= bound) { dk2 = d2; cwp = cw; cwdp = cwd; break; }
        cw  = ncw;
        cwd = __fadd_rn(cwd, __fmul_rn(wv, d2));
      }
    }
    float val = __fadd_rn(cwdp, __fmul_rn(__fadd_rn(bound, -cwp), dk2)) / bound;
    v[b * G784 + g] = sqrtf(fmaxf(val, 0.f));
  }
}

// ---------------------------------------------------------------------------
// Kernel 2: pd0 + landscape features. grid = BATCH, block = 256.
// Basin decomposition + cross-basin-edge Kruskal with elder rule; only local
// minima carry nonzero persistence, so landscapes reduce to top-2 over minima.
// ---------------------------------------------------------------------------
__device__ __forceinline__ unsigned long long pix_key(const float* val_s, int p) {
  // strict total order matching stable argsort of nonneg f32 vals: (val, idx)
  return (((unsigned long long)__float_as_uint(val_s[p])) << 10) | (unsigned)p;
}

__global__ __launch_bounds__(256) void pd0_kernel(const float* __restrict__ v,
                                                  float* __restrict__ feats) {
  __shared__ float val_s[G784];
  __shared__ int   ptr_s[G784];
  __shared__ int   parent[G784];
  __shared__ float deathv[G784];
  __shared__ int   mlist[G784];
  __shared__ unsigned long long edges[2048];
  __shared__ float redf[256];
  __shared__ int   mcnt_sh, ecnt_sh;
  __shared__ float vmax_sh;

  const int tid = threadIdx.x;
  const int b   = blockIdx.x;
  if (tid == 0) { mcnt_sh = 0; ecnt_sh = 0; }

  float pm = -1e30f;
  for (int i = tid; i < G784; i += 256) {
    float x = v[b * G784 + i];
    val_s[i] = x;
    pm = fmaxf(pm, x);
  }
  redf[tid] = pm;
  __syncthreads();
  for (int off = 128; off > 0; off >>= 1) {
    if (tid < off) redf[tid] = fmaxf(redf[tid], redf[tid + off]);
    __syncthreads();
  }
  if (tid == 0) vmax_sh = redf[0];
  __syncthreads();
  const float vmax = vmax_sh;

  // --- descending pointer forest (ptr -> min-key strictly-lower neighbor) ---
  for (int p = tid; p < G784; p += 256) {
    unsigned long long kp = pix_key(val_s, p);
    int i = p / H28, j = p % H28;
    int nb0 = (i > 0)        ? p - H28 : -1;
    int nb1 = (i < H28 - 1)  ? p + H28 : -1;
    int nb2 = (j > 0)        ? p - 1   : -1;
    int nb3 = (j < H28 - 1)  ? p + 1   : -1;
    int nbs[4] = {nb0, nb1, nb2, nb3};
    int best = p;
    unsigned long long bk = kp;
    for (int t = 0; t < 4; t++) {
      int q = nbs[t];
      if (q >= 0) {
        unsigned long long kq = pix_key(val_s, q);
        if (kq < bk) { bk = kq; best = q; }
      }
    }
    ptr_s[p]  = best;
    parent[p] = p;
    deathv[p] = vmax;               // essential / unmerged minima die at max
    if (best == p) {                // local minimum (in (val, idx) order)
      int mi = atomicAdd(&mcnt_sh, 1);
      mlist[mi] = p;
    }
  }
  __syncthreads();

  // --- pointer doubling -> basin roots (10 rounds covers depth 783) ---
  for (int r = 0; r < 10; r++) {
    for (int p = tid; p < G784; p += 256) ptr_s[p] = ptr_s[ptr_s[p]];
    __syncthreads();
  }

  // --- collect cross-basin edges, key = (val[p], p, t, A, B) packed u64 ---
  for (int p = tid; p < G784; p += 256) {
    unsigned long long kp = pix_key(val_s, p);
    int i = p / H28, j = p % H28;
    int nbs[4];
    nbs[0] = (i > 0)       ? p - H28 : -1;
    nbs[1] = (i < H28 - 1) ? p + H28 : -1;
    nbs[2] = (j > 0)       ? p - 1   : -1;
    nbs[3] = (j < H28 - 1) ? p + 1   : -1;
    int bp = ptr_s[p];
    for (int t = 0; t < 4; t++) {
      int q = nbs[t];
      if (q >= 0) {
        unsigned long long kq = pix_key(val_s, q);
        int bq = ptr_s[q];
        if (kq < kp && bq != bp) {
          int e = atomicAdd(&ecnt_sh, 1);
          edges[e] = (((unsigned long long)__float_as_uint(val_s[p])) << 32) |
                     (((unsigned long long)(unsigned)p) << 22) |
                     (((unsigned long long)(unsigned)t) << 20) |
                     (((unsigned long long)(unsigned)bp) << 10) |
                     ((unsigned long long)(unsigned)bq);
        }
      }
    }
  }
  __syncthreads();
  const int ecnt = ecnt_sh;
  const int mcnt = mcnt_sh;

  // --- bitonic sort of edges (pad to pow2) ---
  int n2 = 2;
  while (n2 < ecnt) n2 <<= 1;
  for (int i = ecnt + tid; i < n2; i += 256) edges[i] = ~0ULL;
  __syncthreads();
  for (int kk = 2; kk <= n2; kk <<= 1) {
    for (int jj = kk >> 1; jj > 0; jj >>= 1) {
      for (int i = tid; i < n2; i += 256) {
        int ixj = i ^ jj;
        if (ixj > i) {
          unsigned long long a = edges[i], c = edges[ixj];
          bool up = ((i & kk) == 0);
          if ((a > c) == up) { edges[i] = c; edges[ixj] = a; }
        }
      }
      __syncthreads();
    }
  }

  // --- Kruskal over sorted cross-edges, elder rule (wave 0 only) ---
  if (tid < 64) {
    const int target = mcnt - 1;
    int merged = 0;
    for (int base = 0; base < ecnt && merged < target; base += 64) {
      int i = base + tid;
      bool valid = (i < ecnt);
      unsigned long long e = valid ? edges[i] : 0ULL;
      int A = (int)((e >> 10) & 1023u);
      int B = (int)(e & 1023u);
      int rA = valid ? A : 0;
      int rB = valid ? B : 0;
      for (;;) { int pa = parent[rA]; bool mv = (pa != rA); rA = pa; if (!__any(mv)) break; }
      for (;;) { int pb = parent[rB]; bool mv = (pb != rB); rB = pb; if (!__any(mv)) break; }
      unsigned long long mask = __ballot(valid && (rA != rB));
      while (mask && merged < target) {
        int j = __ffsll(mask) - 1;
        mask &= mask - 1;
        unsigned long long ej = edges[base + j];   // broadcast LDS read
        int Aj = (int)((ej >> 10) & 1023u);
        int Bj = (int)(ej & 1023u);
        int ra = Aj; for (;;) { int pa = parent[ra]; if (pa == ra) break; ra = pa; }
        int rb = Bj; for (;;) { int pb = parent[rb]; if (pb == rb) break; rb = pb; }
        if (ra != rb) {
          unsigned long long ka = pix_key(val_s, ra);
          unsigned long long kb = pix_key(val_s, rb);
          int older   = (ka < kb) ? ra : rb;
          int younger = (ka < kb) ? rb : ra;
          parent[younger] = older;                 // all lanes: same addr/value
          deathv[younger] = __uint_as_float((unsigned)(ej >> 32));
          merged++;
        }
      }
    }
  }
  __syncthreads();

  // --- landscape features: top-2 tents over minima, per t ---
  if (tid < TPTS) {
    float ti = (float)((double)tid * (100.0 / 24.0));
    float t1 = 0.f, t2 = 0.f;
    for (int ii = 0; ii < mcnt; ii++) {
      int m = mlist[ii];
      float tent = fminf(ti - val_s[m], deathv[m] - ti);
      tent = fmaxf(tent, 0.f);
      if (tent > t1)      { t2 = t1; t1 = tent; }
      else if (tent > t2) { t2 = tent; }
    }
    feats[b * NFEAT + tid]        = t1;   // k = 0
    feats[b * NFEAT + TPTS + tid] = t2;   // k = 1
  }
}

// ---------------------------------------------------------------------------
// Kernel 3: dense head. One block of 256.
// xt = feats @ w_land^T + b_land ; signal = sum_b |xt| ;
// out = relu(xt) @ w_fc^T + b_fc
// ---------------------------------------------------------------------------
__global__ __launch_bounds__(256) void head_kernel(const float* __restrict__ feats_g,
                                                   const float* __restrict__ w_land,
                                                   const float* __restrict__ b_land,
                                                   const float* __restrict__ w_fc,
                                                   const float* __restrict__ b_fc,
                                                   float* __restrict__ out) {
  __shared__ float f_s[BATCH * NFEAT];
  __shared__ float xt_s[BATCH * OUTF];
  const int tid = threadIdx.x;
  for (int i = tid; i < BATCH * NFEAT; i += 256) f_s[i] = feats_g[i];
  __syncthreads();
  for (int idx = tid; idx < BATCH * OUTF; idx += 256) {
    int bb = idx / OUTF, ff = idx % OUTF;
    float acc = b_land[ff];
    const float* wr = w_land + ff * NFEAT;
    const float* fr = f_s + bb * NFEAT;
    for (int j = 0; j < NFEAT; j++) acc += fr[j] * wr[j];
    xt_s[idx] = acc;
  }
  __syncthreads();
  if (tid < OUTF) {
    float s = 0.f;
    for (int bb = 0; bb < BATCH; bb++) s += fabsf(xt_s[bb * OUTF + tid]);
    out[BATCH * NCLS + tid] = s;          // signal, after out[32,10]
  }
  for (int idx = tid; idx < BATCH * NCLS; idx += 256) {
    int bb = idx / NCLS, cc = idx % NCLS;
    float acc = b_fc[cc];
    const float* wr = w_fc + cc * OUTF;
    const float* xr = xt_s + bb * OUTF;
    for (int ff = 0; ff < OUTF; ff++) acc += fmaxf(xr[ff], 0.f) * wr[ff];
    out[bb * NCLS + cc] = acc;
  }
}

// ---------------------------------------------------------------------------
extern "C" void kernel_launch(void* const* d_in, const int* in_sizes, int n_in,
                              void* d_out, int out_size, void* d_ws, size_t ws_size,
                              hipStream_t stream) {
  (void)in_sizes; (void)n_in; (void)out_size; (void)ws_size;
  const float* x      = (const float*)d_in[0];   // [32,1,28,28]
  const float* w_land = (const float*)d_in[1];   // [50,50]
  const float* b_land = (const float*)d_in[2];   // [50]
  const float* w_fc   = (const float*)d_in[3];   // [10,50]
  const float* b_fc   = (const float*)d_in[4];   // [10]
  float* out   = (float*)d_out;                  // [32*10] out then [50] signal
  float* v     = (float*)d_ws;                   // [32*784]
  float* feats = v + BATCH * G784;               // [32*50]

  dim3 g2(BATCH, 4);
  dtm_kernel<<<g2, 256, 0, stream>>>(x, v);
  pd0_kernel<<<BATCH, 256, 0, stream>>>(v, feats);
  head_kernel<<<1, 256, 0, stream>>>(feats, w_land, b_land, w_fc, b_fc, out);
}

// Round 2
// 120.916 us; speedup vs baseline: 1.6475x; 1.6475x over previous
//
#include <hip/hip_runtime.h>
#include <math.h>

// Problem constants
#define H28 28
#define G784 784
#define BATCH 32
#define NOFF 3025   // 55*55 lattice offsets (|di|,|dj| <= 27)
#define NOFFP 3072  // padded to multiple of 64
#define NKEY 1459   // keys di*di+dj*dj in [0, 1458]
#define TPTS 25
#define KMAX 2
#define NFEAT 50    // KMAX*TPTS
#define OUTF 50
#define NCLS 10

#define NBX 16      // blocks per batch for dtm
#define BT 512      // threads per dtm block (8 waves)

// ---------------------------------------------------------------------------
// wave64 inclusive scan via DPP (canonical GCN sequence):
// row_shr:1,2,4,8 then row_bcast15 (rows 1,3) and row_bcast31 (rows 2,3).
// bound_ctrl=true -> invalid source lanes read 0; masked rows keep old (=0).
// ---------------------------------------------------------------------------
__device__ __forceinline__ float wave_iscan_f32(float x) {
  int t;
  t = __builtin_amdgcn_update_dpp(0, __float_as_int(x), 0x111, 0xf, 0xf, true);
  x += __int_as_float(t);
  t = __builtin_amdgcn_update_dpp(0, __float_as_int(x), 0x112, 0xf, 0xf, true);
  x += __int_as_float(t);
  t = __builtin_amdgcn_update_dpp(0, __float_as_int(x), 0x114, 0xf, 0xf, true);
  x += __int_as_float(t);
  t = __builtin_amdgcn_update_dpp(0, __float_as_int(x), 0x118, 0xf, 0xf, true);
  x += __int_as_float(t);
  t = __builtin_amdgcn_update_dpp(0, __float_as_int(x), 0x142, 0xa, 0xf, true);
  x += __int_as_float(t);
  t = __builtin_amdgcn_update_dpp(0, __float_as_int(x), 0x143, 0xc, 0xf, true);
  x += __int_as_float(t);
  return x;
}

// ---------------------------------------------------------------------------
// Kernel 1: DTM. grid = (BATCH, NBX), block = BT (8 waves).
// Per block: counting-sorted offset table in LDS (replicated, ~2us), w[b] in
// LDS, block-reduced bound; then ONE WAVE PER PIXEL scans 64 offsets/step
// with dual DPP prefix scans (w, w*d2) and ballot-based crossing detection.
// ---------------------------------------------------------------------------
__global__ __launch_bounds__(BT) void dtm_kernel(const float* __restrict__ x,
                                                 float* __restrict__ v) {
  __shared__ int   hist[NKEY];          // histogram, then scatter cursor
  __shared__ int   seg[BT];
  __shared__ unsigned int ofs_ij[NOFFP];// packed (di,dj) int16 pairs
  __shared__ float ofs_d2[NOFFP];       // f32 (f32 SDIST)^2
  __shared__ float w_s[G784];
  __shared__ float red[BT];

  const int tid = threadIdx.x;
  const int b   = blockIdx.x;
  const int bx  = blockIdx.y;           // 0..NBX-1

  // --- 1. histogram of integer squared distances; init sentinel pad ---
  for (int i = tid; i < NKEY; i += BT) hist[i] = 0;
  for (int i = NOFF + tid; i < NOFFP; i += BT) {
    ofs_ij[i] = 0x00640064u;            // di=dj=100 -> always out of bounds
    ofs_d2[i] = 0.f;
  }
  __syncthreads();
  for (int i = tid; i < NOFF; i += BT) {
    int di = i / 55 - 27, dj = i % 55 - 27;
    atomicAdd(&hist[di * di + dj * dj], 1);
  }
  __syncthreads();

  // --- 2. exclusive scan of hist (segmented + Hillis-Steele over BT) ---
  const int SEG = 3;                    // 3*512 = 1536 >= 1459
  int base0 = tid * SEG;
  int s = 0;
  for (int k = 0; k < SEG; k++) { int idx = base0 + k; if (idx < NKEY) s += hist[idx]; }
  seg[tid] = s;
  __syncthreads();
  for (int off = 1; off < BT; off <<= 1) {
    int add = (tid >= off) ? seg[tid - off] : 0;
    __syncthreads();
    seg[tid] += add;
    __syncthreads();
  }
  int run = seg[tid] - s;
  for (int k = 0; k < SEG; k++) {
    int idx = base0 + k;
    if (idx < NKEY) { int h = hist[idx]; hist[idx] = run; run += h; }
  }
  __syncthreads();

  // --- 3. scatter offsets into sorted-by-key order ---
  for (int i = tid; i < NOFF; i += BT) {
    int di = i / 55 - 27, dj = i % 55 - 27;
    int key = di * di + dj * dj;
    int pos = atomicAdd(&hist[key], 1);
    ofs_ij[pos] = ((unsigned)(di & 0xffff)) | (((unsigned)(dj & 0xffff)) << 16);
    float sd = (float)(sqrt((double)key) * (224.0 / 27.0)); // == f32(SDIST)
    ofs_d2[pos] = sd * sd;                                  // == f32 SDIST**2
  }

  // --- 4. load w[b], block-reduce sum -> bound (barrier also covers step 3) ---
  float ps = 0.f;
  for (int i = tid; i < G784; i += BT) {
    float wv = x[b * G784 + i];
    w_s[i] = wv;
    ps += wv;
  }
  red[tid] = ps;
  __syncthreads();
  for (int off = BT / 2; off > 0; off >>= 1) {
    if (tid < off) red[tid] += red[tid + off];
    __syncthreads();
  }
  const float bound = 0.2f * red[0];

  // --- 5. one wave per pixel, 64 offsets per step, DPP dual prefix scan ---
  const int wave = tid >> 6;            // 0..7
  const int lane = tid & 63;
  const int slot = bx * 8 + wave;       // 0..127

  for (int g = slot; g < G784; g += NBX * 8) {
    const int i1 = g / H28, j1 = g % H28;
    float cw = 0.f, cwd = 0.f;
    float cwp = 0.f, cwdp = 0.f, dk2 = 0.f;
    bool crossed = false;
    for (int base = 0; base < NOFFP && !crossed; base += 64) {
      const int o = base + lane;
      const unsigned ij = ofs_ij[o];
      const float d2 = ofs_d2[o];
      const int di = (short)(ij & 0xffffu);
      const int dj = (short)(ij >> 16);
      const int i2 = i1 + di, j2 = j1 + dj;
      const bool inb = ((unsigned)i2 < (unsigned)H28) & ((unsigned)j2 < (unsigned)H28);
      const float wv = inb ? w_s[i2 * H28 + j2] : 0.f;
      const float wd = wv * d2;
      const float psw = wave_iscan_f32(wv);
      const float psd = wave_iscan_f32(wd);
      const unsigned long long mask = __ballot(cw + psw >= bound);
      if (mask) {
        const int f = __ffsll((unsigned long long)mask) - 1;
        const float psw_f = __shfl(psw, f);
        const float w_f   = __shfl(wv, f);
        const float psd_f = __shfl(psd, f);
        const float wd_f  = __shfl(wd, f);
        dk2  = __shfl(d2, f);
        cwp  = cw + (psw_f - w_f);
        cwdp = cwd + (psd_f - wd_f);
        crossed = true;
      } else {
        cw  += __int_as_float(__builtin_amdgcn_readlane(__float_as_int(psw), 63));
        cwd += __int_as_float(__builtin_amdgcn_readlane(__float_as_int(psd), 63));
      }
    }
    const float val = (cwdp + (bound - cwp) * dk2) / bound;
    if (lane == 0) v[b * G784 + g] = sqrtf(fmaxf(val, 0.f));
  }
}

// ---------------------------------------------------------------------------
// Kernel 2: pd0 + landscape features. grid = BATCH, block = 256.
// (unchanged from the passing round-1 version)
// ---------------------------------------------------------------------------
__device__ __forceinline__ unsigned long long pix_key(const float* val_s, int p) {
  return (((unsigned long long)__float_as_uint(val_s[p])) << 10) | (unsigned)p;
}

__global__ __launch_bounds__(256) void pd0_kernel(const float* __restrict__ v,
                                                  float* __restrict__ feats) {
  __shared__ float val_s[G784];
  __shared__ int   ptr_s[G784];
  __shared__ int   parent[G784];
  __shared__ float deathv[G784];
  __shared__ int   mlist[G784];
  __shared__ unsigned long long edges[2048];
  __shared__ float redf[256];
  __shared__ int   mcnt_sh, ecnt_sh;
  __shared__ float vmax_sh;

  const int tid = threadIdx.x;
  const int b   = blockIdx.x;
  if (tid == 0) { mcnt_sh = 0; ecnt_sh = 0; }

  float pm = -1e30f;
  for (int i = tid; i < G784; i += 256) {
    float xv = v[b * G784 + i];
    val_s[i] = xv;
    pm = fmaxf(pm, xv);
  }
  redf[tid] = pm;
  __syncthreads();
  for (int off = 128; off > 0; off >>= 1) {
    if (tid < off) redf[tid] = fmaxf(redf[tid], redf[tid + off]);
    __syncthreads();
  }
  if (tid == 0) vmax_sh = redf[0];
  __syncthreads();
  const float vmax = vmax_sh;

  for (int p = tid; p < G784; p += 256) {
    unsigned long long kp = pix_key(val_s, p);
    int i = p / H28, j = p % H28;
    int nbs[4];
    nbs[0] = (i > 0)       ? p - H28 : -1;
    nbs[1] = (i < H28 - 1) ? p + H28 : -1;
    nbs[2] = (j > 0)       ? p - 1   : -1;
    nbs[3] = (j < H28 - 1) ? p + 1   : -1;
    int best = p;
    unsigned long long bk = kp;
    for (int t = 0; t < 4; t++) {
      int q = nbs[t];
      if (q >= 0) {
        unsigned long long kq = pix_key(val_s, q);
        if (kq < bk) { bk = kq; best = q; }
      }
    }
    ptr_s[p]  = best;
    parent[p] = p;
    deathv[p] = vmax;
    if (best == p) {
      int mi = atomicAdd(&mcnt_sh, 1);
      mlist[mi] = p;
    }
  }
  __syncthreads();

  for (int r = 0; r < 10; r++) {
    for (int p = tid; p < G784; p += 256) ptr_s[p] = ptr_s[ptr_s[p]];
    __syncthreads();
  }

  for (int p = tid; p < G784; p += 256) {
    unsigned long long kp = pix_key(val_s, p);
    int i = p / H28, j = p % H28;
    int nbs[4];
    nbs[0] = (i > 0)       ? p - H28 : -1;
    nbs[1] = (i < H28 - 1) ? p + H28 : -1;
    nbs[2] = (j > 0)       ? p - 1   : -1;
    nbs[3] = (j < H28 - 1) ? p + 1   : -1;
    int bp = ptr_s[p];
    for (int t = 0; t < 4; t++) {
      int q = nbs[t];
      if (q >= 0) {
        unsigned long long kq = pix_key(val_s, q);
        int bq = ptr_s[q];
        if (kq < kp && bq != bp) {
          int e = atomicAdd(&ecnt_sh, 1);
          edges[e] = (((unsigned long long)__float_as_uint(val_s[p])) << 32) |
                     (((unsigned long long)(unsigned)p) << 22) |
                     (((unsigned long long)(unsigned)t) << 20) |
                     (((unsigned long long)(unsigned)bp) << 10) |
                     ((unsigned long long)(unsigned)bq);
        }
      }
    }
  }
  __syncthreads();
  const int ecnt = ecnt_sh;
  const int mcnt = mcnt_sh;

  int n2 = 2;
  while (n2 < ecnt) n2 <<= 1;
  for (int i = ecnt + tid; i < n2; i += 256) edges[i] = ~0ULL;
  __syncthreads();
  for (int kk = 2; kk <= n2; kk <<= 1) {
    for (int jj = kk >> 1; jj > 0; jj >>= 1) {
      for (int i = tid; i < n2; i += 256) {
        int ixj = i ^ jj;
        if (ixj > i) {
          unsigned long long a = edges[i], c = edges[ixj];
          bool up = ((i & kk) == 0);
          if ((a > c) == up) { edges[i] = c; edges[ixj] = a; }
        }
      }
      __syncthreads();
    }
  }

  if (tid < 64) {
    const int target = mcnt - 1;
    int merged = 0;
    for (int base = 0; base < ecnt && merged < target; base += 64) {
      int i = base + tid;
      bool valid = (i < ecnt);
      unsigned long long e = valid ? edges[i] : 0ULL;
      int A = (int)((e >> 10) & 1023u);
      int B = (int)(e & 1023u);
      int rA = valid ? A : 0;
      int rB = valid ? B : 0;
      for (;;) { int pa = parent[rA]; bool mv = (pa != rA); rA = pa; if (!__any(mv)) break; }
      for (;;) { int pb = parent[rB]; bool mv = (pb != rB); rB = pb; if (!__any(mv)) break; }
      unsigned long long mask = __ballot(valid && (rA != rB));
      while (mask && merged < target) {
        int j = __ffsll(mask) - 1;
        mask &= mask - 1;
        unsigned long long ej = edges[base + j];
        int Aj = (int)((ej >> 10) & 1023u);
        int Bj = (int)(ej & 1023u);
        int ra = Aj; for (;;) { int pa = parent[ra]; if (pa == ra) break; ra = pa; }
        int rb = Bj; for (;;) { int pb = parent[rb]; if (pb == rb) break; rb = pb; }
        if (ra != rb) {
          unsigned long long ka = pix_key(val_s, ra);
          unsigned long long kb = pix_key(val_s, rb);
          int older   = (ka < kb) ? ra : rb;
          int younger = (ka < kb) ? rb : ra;
          parent[younger] = older;
          deathv[younger] = __uint_as_float((unsigned)(ej >> 32));
          merged++;
        }
      }
    }
  }
  __syncthreads();

  if (tid < TPTS) {
    float ti = (float)((double)tid * (100.0 / 24.0));
    float t1 = 0.f, t2 = 0.f;
    for (int ii = 0; ii < mcnt; ii++) {
      int m = mlist[ii];
      float tent = fminf(ti - val_s[m], deathv[m] - ti);
      tent = fmaxf(tent, 0.f);
      if (tent > t1)      { t2 = t1; t1 = tent; }
      else if (tent > t2) { t2 = tent; }
    }
    feats[b * NFEAT + tid]        = t1;
    feats[b * NFEAT + TPTS + tid] = t2;
  }
}

// ---------------------------------------------------------------------------
// Kernel 3: dense head (unchanged).
// ---------------------------------------------------------------------------
__global__ __launch_bounds__(256) void head_kernel(const float* __restrict__ feats_g,
                                                   const float* __restrict__ w_land,
                                                   const float* __restrict__ b_land,
                                                   const float* __restrict__ w_fc,
                                                   const float* __restrict__ b_fc,
                                                   float* __restrict__ out) {
  __shared__ float f_s[BATCH * NFEAT];
  __shared__ float xt_s[BATCH * OUTF];
  const int tid = threadIdx.x;
  for (int i = tid; i < BATCH * NFEAT; i += 256) f_s[i] = feats_g[i];
  __syncthreads();
  for (int idx = tid; idx < BATCH * OUTF; idx += 256) {
    int bb = idx / OUTF, ff = idx % OUTF;
    float acc = b_land[ff];
    const float* wr = w_land + ff * NFEAT;
    const float* fr = f_s + bb * NFEAT;
    for (int j = 0; j < NFEAT; j++) acc += fr[j] * wr[j];
    xt_s[idx] = acc;
  }
  __syncthreads();
  if (tid < OUTF) {
    float s = 0.f;
    for (int bb = 0; bb < BATCH; bb++) s += fabsf(xt_s[bb * OUTF + tid]);
    out[BATCH * NCLS + tid] = s;
  }
  for (int idx = tid; idx < BATCH * NCLS; idx += 256) {
    int bb = idx / NCLS, cc = idx % NCLS;
    float acc = b_fc[cc];
    const float* wr = w_fc + cc * OUTF;
    const float* xr = xt_s + bb * OUTF;
    for (int ff = 0; ff < OUTF; ff++) acc += fmaxf(xr[ff], 0.f) * wr[ff];
    out[bb * NCLS + cc] = acc;
  }
}

// ---------------------------------------------------------------------------
extern "C" void kernel_launch(void* const* d_in, const int* in_sizes, int n_in,
                              void* d_out, int out_size, void* d_ws, size_t ws_size,
                              hipStream_t stream) {
  (void)in_sizes; (void)n_in; (void)out_size; (void)ws_size;
  const float* x      = (const float*)d_in[0];   // [32,1,28,28]
  const float* w_land = (const float*)d_in[1];   // [50,50]
  const float* b_land = (const float*)d_in[2];   // [50]
  const float* w_fc   = (const float*)d_in[3];   // [10,50]
  const float* b_fc   = (const float*)d_in[4];   // [10]
  float* out   = (float*)d_out;                  // [32*10] out then [50] signal
  float* v     = (float*)d_ws;                   // [32*784]
  float* feats = v + BATCH * G784;               // [32*50]

  dim3 g1(BATCH, NBX);
  dtm_kernel<<<g1, BT, 0, stream>>>(x, v);
  pd0_kernel<<<BATCH, 256, 0, stream>>>(v, feats);
  head_kernel<<<1, 256, 0, stream>>>(feats, w_land, b_land, w_fc, b_fc, out);
}

// Round 3
// 115.126 us; speedup vs baseline: 1.7304x; 1.0503x over previous
//
#include <hip/hip_runtime.h>
#include <math.h>

// Problem constants
#define H28 28
#define G784 784
#define BATCH 32
#define NOFF 3025   // 55*55 lattice offsets (|di|,|dj| <= 27)
#define NOFFP 3072  // padded to multiple of 64
#define NKEY 1459   // keys di*di+dj*dj in [0, 1458]
#define TPTS 25
#define KMAX 2
#define NFEAT 50    // KMAX*TPTS
#define OUTF 50
#define NCLS 10

#define NBX 16      // blocks per batch for dtm
#define BT 512      // threads per dtm block (8 waves)
#define BT2 512     // threads per pd0 block

// ---------------------------------------------------------------------------
// Compile-time counting-sorted offset table (replaces per-block hist/scan/
// scatter preamble). d2 reproduces f32(sqrt(key)*(224/27))^2 via constexpr
// Newton sqrt in double (<=1 ulp in double -> float rounding unchanged).
// ---------------------------------------------------------------------------
struct OffPair { unsigned ij; float d2; };
struct OffTab  { OffPair e[NOFFP]; };

constexpr double csqrt(double x) {
  double r = x * 0.5 + 1.0;
  for (int i = 0; i < 20; i++) r = 0.5 * (r + x / r);
  return r;
}

constexpr OffTab make_offtab() {
  OffTab t{};
  int start[NKEY] = {};
  for (int i = 0; i < NOFF; i++) {
    int di = i / 55 - 27, dj = i % 55 - 27;
    start[di * di + dj * dj]++;
  }
  int run = 0;
  for (int k = 0; k < NKEY; k++) { int h = start[k]; start[k] = run; run += h; }
  for (int i = 0; i < NOFF; i++) {
    int di = i / 55 - 27, dj = i % 55 - 27;
    int key = di * di + dj * dj;
    int pos = start[key]++;
    float sd = (key == 0) ? 0.0f : (float)(csqrt((double)key) * (224.0 / 27.0));
    t.e[pos].ij = ((unsigned)(di & 0xffff)) | (((unsigned)(dj & 0xffff)) << 16);
    t.e[pos].d2 = sd * sd;
  }
  for (int i = NOFF; i < NOFFP; i++) { t.e[i].ij = 0x00640064u; t.e[i].d2 = 0.f; }
  return t;
}

__device__ constexpr OffTab OFFTAB = make_offtab();

// ---------------------------------------------------------------------------
// wave64 inclusive scan via DPP (row_shr 1,2,4,8; row_bcast15/31).
// ---------------------------------------------------------------------------
__device__ __forceinline__ float wave_iscan_f32(float x) {
  int t;
  t = __builtin_amdgcn_update_dpp(0, __float_as_int(x), 0x111, 0xf, 0xf, true);
  x += __int_as_float(t);
  t = __builtin_amdgcn_update_dpp(0, __float_as_int(x), 0x112, 0xf, 0xf, true);
  x += __int_as_float(t);
  t = __builtin_amdgcn_update_dpp(0, __float_as_int(x), 0x114, 0xf, 0xf, true);
  x += __int_as_float(t);
  t = __builtin_amdgcn_update_dpp(0, __float_as_int(x), 0x118, 0xf, 0xf, true);
  x += __int_as_float(t);
  t = __builtin_amdgcn_update_dpp(0, __float_as_int(x), 0x142, 0xa, 0xf, true);
  x += __int_as_float(t);
  t = __builtin_amdgcn_update_dpp(0, __float_as_int(x), 0x143, 0xc, 0xf, true);
  x += __int_as_float(t);
  return x;
}

// ---------------------------------------------------------------------------
// Kernel 1: DTM. grid = (BATCH, NBX), block = BT. One wave per pixel,
// 64 offsets per step, dual DPP prefix scans, pipelined table loads.
// Also zeroes the pd0 done-counter (block 0 only).
// ---------------------------------------------------------------------------
__global__ __launch_bounds__(BT) void dtm_kernel(const float* __restrict__ x,
                                                 float* __restrict__ v,
                                                 int* __restrict__ done_ctr) {
  __shared__ float w_s[G784];
  __shared__ float red[BT];

  const int tid = threadIdx.x;
  const int b   = blockIdx.x;
  const int bx  = blockIdx.y;

  if (b == 0 && bx == 0 && tid == 0) *done_ctr = 0;

  // load w[b], block-reduce sum -> bound
  float ps = 0.f;
  for (int i = tid; i < G784; i += BT) {
    float wv = x[b * G784 + i];
    w_s[i] = wv;
    ps += wv;
  }
  red[tid] = ps;
  __syncthreads();
  for (int off = BT / 2; off > 0; off >>= 1) {
    if (tid < off) red[tid] += red[tid + off];
    __syncthreads();
  }
  const float bound = 0.2f * red[0];

  const int wave = tid >> 6;
  const int lane = tid & 63;
  const int slot = bx * 8 + wave;       // 0..127

  for (int g = slot; g < G784; g += NBX * 8) {
    const int i1 = g / H28, j1 = g % H28;
    float cw = 0.f, cwd = 0.f;
    float cwp = 0.f, cwdp = 0.f, dk2 = 0.f;
    bool crossed = false;
    int o = lane;
    unsigned ij = OFFTAB.e[o].ij;
    float d2v   = OFFTAB.e[o].d2;
    for (int base = 0; base < NOFFP && !crossed; base += 64) {
      int onext = o + 64;
      if (onext >= NOFFP) onext = o;
      const unsigned ij_n = OFFTAB.e[onext].ij;  // prefetch next chunk
      const float    d2_n = OFFTAB.e[onext].d2;
      const int di = (short)(ij & 0xffffu);
      const int dj = (short)(ij >> 16);
      const int i2 = i1 + di, j2 = j1 + dj;
      const bool inb = ((unsigned)i2 < (unsigned)H28) & ((unsigned)j2 < (unsigned)H28);
      const float wv = inb ? w_s[i2 * H28 + j2] : 0.f;
      const float wd = wv * d2v;
      const float psw = wave_iscan_f32(wv);
      const float psd = wave_iscan_f32(wd);
      const unsigned long long mask = __ballot(cw + psw >= bound);
      if (mask) {
        const int f = __ffsll((unsigned long long)mask) - 1;
        const float psw_f = __shfl(psw, f);
        const float w_f   = __shfl(wv, f);
        const float psd_f = __shfl(psd, f);
        const float wd_f  = __shfl(wd, f);
        dk2  = __shfl(d2v, f);
        cwp  = cw + (psw_f - w_f);
        cwdp = cwd + (psd_f - wd_f);
        crossed = true;
      } else {
        cw  += __int_as_float(__builtin_amdgcn_readlane(__float_as_int(psw), 63));
        cwd += __int_as_float(__builtin_amdgcn_readlane(__float_as_int(psd), 63));
      }
      ij = ij_n; d2v = d2_n; o = onext;
    }
    const float val = (cwdp + (bound - cwp) * dk2) / bound;
    if (lane == 0) v[b * G784 + g] = sqrtf(fmaxf(val, 0.f));
  }
}

// ---------------------------------------------------------------------------
// Kernel 2: pd0 + landscape + (last block) dense head.
// grid = BATCH, block = BT2.
// ---------------------------------------------------------------------------
__device__ __forceinline__ unsigned long long pix_key(const float* val_s, int p) {
  return (((unsigned long long)__float_as_uint(val_s[p])) << 10) | (unsigned)p;
}

__global__ __launch_bounds__(BT2) void pd0_kernel(const float* __restrict__ v,
                                                  float* __restrict__ feats,
                                                  int* __restrict__ done_ctr,
                                                  const float* __restrict__ w_land,
                                                  const float* __restrict__ b_land,
                                                  const float* __restrict__ w_fc,
                                                  const float* __restrict__ b_fc,
                                                  float* __restrict__ out) {
  __shared__ float val_s[G784];
  __shared__ int   ptr_s[G784];
  __shared__ int   parent[G784];
  __shared__ float deathv[G784];
  __shared__ int   mlist[G784];
  __shared__ unsigned long long edges[2048];
  __shared__ float redf[BT2];
  __shared__ int   mcnt_sh, ecnt_sh, last_sh;
  __shared__ float vmax_sh;
  __shared__ float f_s[BATCH * NFEAT];
  __shared__ float xt_s[BATCH * OUTF];

  const int tid = threadIdx.x;
  const int b   = blockIdx.x;
  if (tid == 0) { mcnt_sh = 0; ecnt_sh = 0; }

  float pm = -1e30f;
  for (int i = tid; i < G784; i += BT2) {
    float xv = v[b * G784 + i];
    val_s[i] = xv;
    pm = fmaxf(pm, xv);
  }
  redf[tid] = pm;
  __syncthreads();
  for (int off = BT2 / 2; off > 0; off >>= 1) {
    if (tid < off) redf[tid] = fmaxf(redf[tid], redf[tid + off]);
    __syncthreads();
  }
  if (tid == 0) vmax_sh = redf[0];
  __syncthreads();
  const float vmax = vmax_sh;

  // descending pointer forest
  for (int p = tid; p < G784; p += BT2) {
    unsigned long long kp = pix_key(val_s, p);
    int i = p / H28, j = p % H28;
    int nbs[4];
    nbs[0] = (i > 0)       ? p - H28 : -1;
    nbs[1] = (i < H28 - 1) ? p + H28 : -1;
    nbs[2] = (j > 0)       ? p - 1   : -1;
    nbs[3] = (j < H28 - 1) ? p + 1   : -1;
    int best = p;
    unsigned long long bk = kp;
    for (int t = 0; t < 4; t++) {
      int q = nbs[t];
      if (q >= 0) {
        unsigned long long kq = pix_key(val_s, q);
        if (kq < bk) { bk = kq; best = q; }
      }
    }
    ptr_s[p]  = best;
    parent[p] = p;
    deathv[p] = vmax;
    if (best == p) {
      int mi = atomicAdd(&mcnt_sh, 1);
      mlist[mi] = p;
    }
  }
  __syncthreads();

  // pointer doubling -> basin roots
  for (int r = 0; r < 10; r++) {
    for (int p = tid; p < G784; p += BT2) ptr_s[p] = ptr_s[ptr_s[p]];
    __syncthreads();
  }

  // cross-basin edges, key = (val[p], p, t) packed
  for (int p = tid; p < G784; p += BT2) {
    unsigned long long kp = pix_key(val_s, p);
    int i = p / H28, j = p % H28;
    int nbs[4];
    nbs[0] = (i > 0)       ? p - H28 : -1;
    nbs[1] = (i < H28 - 1) ? p + H28 : -1;
    nbs[2] = (j > 0)       ? p - 1   : -1;
    nbs[3] = (j < H28 - 1) ? p + 1   : -1;
    int bp = ptr_s[p];
    for (int t = 0; t < 4; t++) {
      int q = nbs[t];
      if (q >= 0) {
        unsigned long long kq = pix_key(val_s, q);
        int bq = ptr_s[q];
        if (kq < kp && bq != bp) {
          int e = atomicAdd(&ecnt_sh, 1);
          if (e < 2048)
            edges[e] = (((unsigned long long)__float_as_uint(val_s[p])) << 32) |
                       (((unsigned long long)(unsigned)p) << 22) |
                       (((unsigned long long)(unsigned)t) << 20) |
                       (((unsigned long long)(unsigned)bp) << 10) |
                       ((unsigned long long)(unsigned)bq);
        }
      }
    }
  }
  __syncthreads();
  const int ecnt = (ecnt_sh < 2048) ? ecnt_sh : 2048;
  const int mcnt = mcnt_sh;

  // bitonic sort of edges
  int n2 = 2;
  while (n2 < ecnt) n2 <<= 1;
  for (int i = ecnt + tid; i < n2; i += BT2) edges[i] = ~0ULL;
  __syncthreads();
  for (int kk = 2; kk <= n2; kk <<= 1) {
    for (int jj = kk >> 1; jj > 0; jj >>= 1) {
      for (int i = tid; i < n2; i += BT2) {
        int ixj = i ^ jj;
        if (ixj > i) {
          unsigned long long a = edges[i], c = edges[ixj];
          bool up = ((i & kk) == 0);
          if ((a > c) == up) { edges[i] = c; edges[ixj] = a; }
        }
      }
      __syncthreads();
    }
  }

  // Kruskal, elder rule (wave 0)
  if (tid < 64) {
    const int target = mcnt - 1;
    int merged = 0;
    for (int base = 0; base < ecnt && merged < target; base += 64) {
      int i = base + tid;
      bool valid = (i < ecnt);
      unsigned long long e = valid ? edges[i] : 0ULL;
      int A = (int)((e >> 10) & 1023u);
      int B = (int)(e & 1023u);
      int rA = valid ? A : 0;
      int rB = valid ? B : 0;
      for (;;) { int pa = parent[rA]; bool mv = (pa != rA); rA = pa; if (!__any(mv)) break; }
      for (;;) { int pb = parent[rB]; bool mv = (pb != rB); rB = pb; if (!__any(mv)) break; }
      unsigned long long mask = __ballot(valid && (rA != rB));
      while (mask && merged < target) {
        int j = __ffsll(mask) - 1;
        mask &= mask - 1;
        unsigned long long ej = edges[base + j];
        int Aj = (int)((ej >> 10) & 1023u);
        int Bj = (int)(ej & 1023u);
        int ra = Aj; for (;;) { int pa = parent[ra]; if (pa == ra) break; ra = pa; }
        int rb = Bj; for (;;) { int pb = parent[rb]; if (pb == rb) break; rb = pb; }
        if (ra != rb) {
          unsigned long long ka = pix_key(val_s, ra);
          unsigned long long kb = pix_key(val_s, rb);
          int older   = (ka < kb) ? ra : rb;
          int younger = (ka < kb) ? rb : ra;
          parent[younger] = older;
          deathv[younger] = __uint_as_float((unsigned)(ej >> 32));
          merged++;
        }
      }
    }
  }
  __syncthreads();

  // landscape features: top-2 tents over minima per t
  if (tid < TPTS) {
    float ti = (float)((double)tid * (100.0 / 24.0));
    float t1 = 0.f, t2 = 0.f;
    for (int ii = 0; ii < mcnt; ii++) {
      int m = mlist[ii];
      float tent = fminf(ti - val_s[m], deathv[m] - ti);
      tent = fmaxf(tent, 0.f);
      if (tent > t1)      { t2 = t1; t1 = tent; }
      else if (tent > t2) { t2 = tent; }
    }
    feats[b * NFEAT + tid]        = t1;
    feats[b * NFEAT + TPTS + tid] = t2;
  }

  // ---- last block computes the dense head ----
  __threadfence();     // release feats stores to device scope
  __syncthreads();
  if (tid == 0) last_sh = (atomicAdd(done_ctr, 1) == BATCH - 1) ? 1 : 0;
  __syncthreads();
  if (!last_sh) return;
  __threadfence();     // acquire

  for (int i = tid; i < BATCH * NFEAT; i += BT2) f_s[i] = feats[i];
  __syncthreads();
  for (int idx = tid; idx < BATCH * OUTF; idx += BT2) {
    int bb = idx / OUTF, ff = idx % OUTF;
    float acc = b_land[ff];
    const float* wr = w_land + ff * NFEAT;
    const float* fr = f_s + bb * NFEAT;
    for (int j = 0; j < NFEAT; j++) acc += fr[j] * wr[j];
    xt_s[idx] = acc;
  }
  __syncthreads();
  if (tid < OUTF) {
    float s = 0.f;
    for (int bb = 0; bb < BATCH; bb++) s += fabsf(xt_s[bb * OUTF + tid]);
    out[BATCH * NCLS + tid] = s;
  }
  for (int idx = tid; idx < BATCH * NCLS; idx += BT2) {
    int bb = idx / NCLS, cc = idx % NCLS;
    float acc = b_fc[cc];
    const float* wr = w_fc + cc * OUTF;
    const float* xr = xt_s + bb * OUTF;
    for (int ff = 0; ff < OUTF; ff++) acc += fmaxf(xr[ff], 0.f) * wr[ff];
    out[bb * NCLS + cc] = acc;
  }
}

// ---------------------------------------------------------------------------
extern "C" void kernel_launch(void* const* d_in, const int* in_sizes, int n_in,
                              void* d_out, int out_size, void* d_ws, size_t ws_size,
                              hipStream_t stream) {
  (void)in_sizes; (void)n_in; (void)out_size; (void)ws_size;
  const float* x      = (const float*)d_in[0];   // [32,1,28,28]
  const float* w_land = (const float*)d_in[1];   // [50,50]
  const float* b_land = (const float*)d_in[2];   // [50]
  const float* w_fc   = (const float*)d_in[3];   // [10,50]
  const float* b_fc   = (const float*)d_in[4];   // [10]
  float* out   = (float*)d_out;                  // [32*10] out then [50] signal
  float* v     = (float*)d_ws;                   // [32*784]
  float* feats = v + BATCH * G784;               // [32*50]
  int*   done  = (int*)(feats + BATCH * NFEAT);  // [1]

  dim3 g1(BATCH, NBX);
  dtm_kernel<<<g1, BT, 0, stream>>>(x, v, done);
  pd0_kernel<<<BATCH, BT2, 0, stream>>>(v, feats, done,
                                        w_land, b_land, w_fc, b_fc, out);
}

// Round 4
// 100.486 us; speedup vs baseline: 1.9825x; 1.1457x over previous
//
#include <hip/hip_runtime.h>
#include <math.h>

// Problem constants
#define H28 28
#define G784 784
#define BATCH 32
#define NOFF 3025   // 55*55 lattice offsets (|di|,|dj| <= 27)
#define NOFFP 3072  // padded to multiple of 64
#define NKEY 1459   // keys di*di+dj*dj in [0, 1458]
#define TPTS 25
#define KMAX 2
#define NFEAT 50    // KMAX*TPTS
#define OUTF 50
#define NCLS 10

#define NBX 16      // blocks per batch for dtm
#define BT 512      // threads per dtm block (8 waves)
#define BT2 512     // threads per pd0 block
#define HS 2048     // edge-dedup hash slots (pow2)
#define EMAX 1024   // deduped edge capacity (planar bound ~3*mcnt)

// ---------------------------------------------------------------------------
// Compile-time counting-sorted offset table. d2 reproduces
// f32(sqrt(key)*(224/27))^2 via constexpr Newton sqrt in double.
// ---------------------------------------------------------------------------
struct OffPair { unsigned ij; float d2; };
struct OffTab  { OffPair e[NOFFP]; };

constexpr double csqrt(double x) {
  double r = x * 0.5 + 1.0;
  for (int i = 0; i < 20; i++) r = 0.5 * (r + x / r);
  return r;
}

constexpr OffTab make_offtab() {
  OffTab t{};
  int start[NKEY] = {};
  for (int i = 0; i < NOFF; i++) {
    int di = i / 55 - 27, dj = i % 55 - 27;
    start[di * di + dj * dj]++;
  }
  int run = 0;
  for (int k = 0; k < NKEY; k++) { int h = start[k]; start[k] = run; run += h; }
  for (int i = 0; i < NOFF; i++) {
    int di = i / 55 - 27, dj = i % 55 - 27;
    int key = di * di + dj * dj;
    int pos = start[key]++;
    float sd = (key == 0) ? 0.0f : (float)(csqrt((double)key) * (224.0 / 27.0));
    t.e[pos].ij = ((unsigned)(di & 0xffff)) | (((unsigned)(dj & 0xffff)) << 16);
    t.e[pos].d2 = sd * sd;
  }
  for (int i = NOFF; i < NOFFP; i++) { t.e[i].ij = 0x00640064u; t.e[i].d2 = 0.f; }
  return t;
}

__device__ constexpr OffTab OFFTAB = make_offtab();

// ---------------------------------------------------------------------------
// wave64 inclusive scan via DPP (row_shr 1,2,4,8; row_bcast15/31).
// ---------------------------------------------------------------------------
__device__ __forceinline__ float wave_iscan_f32(float x) {
  int t;
  t = __builtin_amdgcn_update_dpp(0, __float_as_int(x), 0x111, 0xf, 0xf, true);
  x += __int_as_float(t);
  t = __builtin_amdgcn_update_dpp(0, __float_as_int(x), 0x112, 0xf, 0xf, true);
  x += __int_as_float(t);
  t = __builtin_amdgcn_update_dpp(0, __float_as_int(x), 0x114, 0xf, 0xf, true);
  x += __int_as_float(t);
  t = __builtin_amdgcn_update_dpp(0, __float_as_int(x), 0x118, 0xf, 0xf, true);
  x += __int_as_float(t);
  t = __builtin_amdgcn_update_dpp(0, __float_as_int(x), 0x142, 0xa, 0xf, true);
  x += __int_as_float(t);
  t = __builtin_amdgcn_update_dpp(0, __float_as_int(x), 0x143, 0xc, 0xf, true);
  x += __int_as_float(t);
  return x;
}

// ---------------------------------------------------------------------------
// Kernel 1: DTM (unchanged from round 3). grid=(BATCH,NBX), block=BT.
// ---------------------------------------------------------------------------
__global__ __launch_bounds__(BT) void dtm_kernel(const float* __restrict__ x,
                                                 float* __restrict__ v,
                                                 int* __restrict__ done_ctr) {
  __shared__ float w_s[G784];
  __shared__ float red[BT];

  const int tid = threadIdx.x;
  const int b   = blockIdx.x;
  const int bx  = blockIdx.y;

  if (b == 0 && bx == 0 && tid == 0) *done_ctr = 0;

  float ps = 0.f;
  for (int i = tid; i < G784; i += BT) {
    float wv = x[b * G784 + i];
    w_s[i] = wv;
    ps += wv;
  }
  red[tid] = ps;
  __syncthreads();
  for (int off = BT / 2; off > 0; off >>= 1) {
    if (tid < off) red[tid] += red[tid + off];
    __syncthreads();
  }
  const float bound = 0.2f * red[0];

  const int wave = tid >> 6;
  const int lane = tid & 63;
  const int slot = bx * 8 + wave;

  for (int g = slot; g < G784; g += NBX * 8) {
    const int i1 = g / H28, j1 = g % H28;
    float cw = 0.f, cwd = 0.f;
    float cwp = 0.f, cwdp = 0.f, dk2 = 0.f;
    bool crossed = false;
    int o = lane;
    unsigned ij = OFFTAB.e[o].ij;
    float d2v   = OFFTAB.e[o].d2;
    for (int base = 0; base < NOFFP && !crossed; base += 64) {
      int onext = o + 64;
      if (onext >= NOFFP) onext = o;
      const unsigned ij_n = OFFTAB.e[onext].ij;
      const float    d2_n = OFFTAB.e[onext].d2;
      const int di = (short)(ij & 0xffffu);
      const int dj = (short)(ij >> 16);
      const int i2 = i1 + di, j2 = j1 + dj;
      const bool inb = ((unsigned)i2 < (unsigned)H28) & ((unsigned)j2 < (unsigned)H28);
      const float wv = inb ? w_s[i2 * H28 + j2] : 0.f;
      const float wd = wv * d2v;
      const float psw = wave_iscan_f32(wv);
      const float psd = wave_iscan_f32(wd);
      const unsigned long long mask = __ballot(cw + psw >= bound);
      if (mask) {
        const int f = __ffsll((unsigned long long)mask) - 1;
        const float psw_f = __shfl(psw, f);
        const float w_f   = __shfl(wv, f);
        const float psd_f = __shfl(psd, f);
        const float wd_f  = __shfl(wd, f);
        dk2  = __shfl(d2v, f);
        cwp  = cw + (psw_f - w_f);
        cwdp = cwd + (psd_f - wd_f);
        crossed = true;
      } else {
        cw  += __int_as_float(__builtin_amdgcn_readlane(__float_as_int(psw), 63));
        cwd += __int_as_float(__builtin_amdgcn_readlane(__float_as_int(psd), 63));
      }
      ij = ij_n; d2v = d2_n; o = onext;
    }
    const float val = (cwdp + (bound - cwp) * dk2) / bound;
    if (lane == 0) v[b * G784 + g] = sqrtf(fmaxf(val, 0.f));
  }
}

// ---------------------------------------------------------------------------
// Kernel 2: pd0 + landscape + (last block) dense head. grid=BATCH, block=BT2.
// Dedup cross-basin edges via LDS hash -> small bitonic (wave-synchronous)
// -> claim-based parallel Kruskal (rank + halving + oldest-key elder rule).
// ---------------------------------------------------------------------------
__device__ __forceinline__ unsigned long long pix_key(const float* val_s, int p) {
  return (((unsigned long long)__float_as_uint(val_s[p])) << 10) | (unsigned)p;
}

__global__ __launch_bounds__(BT2) void pd0_kernel(const float* __restrict__ v,
                                                  float* __restrict__ feats,
                                                  int* __restrict__ done_ctr,
                                                  const float* __restrict__ w_land,
                                                  const float* __restrict__ b_land,
                                                  const float* __restrict__ w_fc,
                                                  const float* __restrict__ b_fc,
                                                  float* __restrict__ out) {
  __shared__ float val_s[G784];
  __shared__ int   ptr_s[G784];
  __shared__ int   parent[G784];
  __shared__ unsigned rank_s[G784];
  __shared__ unsigned claims[G784];
  __shared__ float deathv[G784];
  __shared__ int   mlist[G784];
  __shared__ unsigned long long oldkey[G784];
  __shared__ unsigned htag[HS];
  __shared__ unsigned long long hval[HS];
  __shared__ unsigned long long edges[EMAX];
  __shared__ float redf[BT2];
  __shared__ int   mcnt_sh, ecnt_sh, last_sh;
  __shared__ float vmax_sh;
  __shared__ float f_s[BATCH * NFEAT];
  __shared__ float xt_s[BATCH * OUTF];

  const int tid = threadIdx.x;
  const int b   = blockIdx.x;
  if (tid == 0) { mcnt_sh = 0; ecnt_sh = 0; }

  // init hash + union-find aux
  for (int i = tid; i < HS; i += BT2) { htag[i] = 0u; hval[i] = ~0ULL; }

  float pm = -1e30f;
  for (int i = tid; i < G784; i += BT2) {
    float xv = v[b * G784 + i];
    val_s[i] = xv;
    pm = fmaxf(pm, xv);
    rank_s[i] = 0u;
    claims[i] = 0xFFFFFFFFu;
  }
  redf[tid] = pm;
  __syncthreads();
  for (int off = BT2 / 2; off > 0; off >>= 1) {
    if (tid < off) redf[tid] = fmaxf(redf[tid], redf[tid + off]);
    __syncthreads();
  }
  if (tid == 0) vmax_sh = redf[0];
  __syncthreads();
  const float vmax = vmax_sh;

  // descending pointer forest; register minima
  for (int p = tid; p < G784; p += BT2) {
    unsigned long long kp = pix_key(val_s, p);
    int i = p / H28, j = p % H28;
    int nbs[4];
    nbs[0] = (i > 0)       ? p - H28 : -1;
    nbs[1] = (i < H28 - 1) ? p + H28 : -1;
    nbs[2] = (j > 0)       ? p - 1   : -1;
    nbs[3] = (j < H28 - 1) ? p + 1   : -1;
    int best = p;
    unsigned long long bk = kp;
    for (int t = 0; t < 4; t++) {
      int q = nbs[t];
      if (q >= 0) {
        unsigned long long kq = pix_key(val_s, q);
        if (kq < bk) { bk = kq; best = q; }
      }
    }
    ptr_s[p]  = best;
    parent[p] = p;
    deathv[p] = vmax;
    if (best == p) {
      oldkey[p] = kp;
      int mi = atomicAdd(&mcnt_sh, 1);
      mlist[mi] = p;
    }
  }
  __syncthreads();

  // pointer doubling -> basin roots
  for (int r = 0; r < 10; r++) {
    for (int p = tid; p < G784; p += BT2) ptr_s[p] = ptr_s[ptr_s[p]];
    __syncthreads();
  }

  // cross-basin edges -> hash dedup: per unordered basin pair keep min
  // (val,p,t) key. Kruskal on per-pair-min simple graph == on multigraph.
  for (int p = tid; p < G784; p += BT2) {
    unsigned long long kp = pix_key(val_s, p);
    int i = p / H28, j = p % H28;
    int nbs[4];
    nbs[0] = (i > 0)       ? p - H28 : -1;
    nbs[1] = (i < H28 - 1) ? p + H28 : -1;
    nbs[2] = (j > 0)       ? p - 1   : -1;
    nbs[3] = (j < H28 - 1) ? p + 1   : -1;
    int bp = ptr_s[p];
    for (int t = 0; t < 4; t++) {
      int q = nbs[t];
      if (q >= 0) {
        unsigned long long kq = pix_key(val_s, q);
        int bq = ptr_s[q];
        if (kq < kp && bq != bp) {
          unsigned long long key =
              (((unsigned long long)__float_as_uint(val_s[p])) << 32) |
              (((unsigned long long)(unsigned)p) << 22) |
              (((unsigned long long)(unsigned)t) << 20) |
              (((unsigned long long)(unsigned)bp) << 10) |
              ((unsigned long long)(unsigned)bq);
          unsigned lo = (bp < bq) ? (unsigned)bp : (unsigned)bq;
          unsigned hi = (bp < bq) ? (unsigned)bq : (unsigned)bp;
          unsigned pairid = (lo << 10) | hi;
          unsigned idx = (pairid * 2654435761u) >> 21;   // HS=2048
          for (;;) {
            unsigned t0 = atomicCAS(&htag[idx], 0u, pairid + 1u);
            if (t0 == 0u || t0 == pairid + 1u) { atomicMin(&hval[idx], key); break; }
            idx = (idx + 1) & (HS - 1);
          }
        }
      }
    }
  }
  __syncthreads();

  // compact hash -> edges
  for (int i = tid; i < HS; i += BT2) {
    if (htag[i]) {
      int e = atomicAdd(&ecnt_sh, 1);
      if (e < EMAX) edges[e] = hval[i];
    }
  }
  __syncthreads();
  const int ne   = (ecnt_sh < EMAX) ? ecnt_sh : EMAX;
  const int mcnt = mcnt_sh;
  const int wave = tid >> 6;
  const int lane = tid & 63;

  // ---- wave 0: sort + Kruskal (wave-synchronous; fences not barriers) ----
  if (wave == 0) {
    if (ne > 1) {
      int n2 = 1;
      while (n2 < ne) n2 <<= 1;
      for (int i = ne + lane; i < n2; i += 64) edges[i] = ~0ULL;
      __threadfence_block();
      for (int kk = 2; kk <= n2; kk <<= 1) {
        for (int jj = kk >> 1; jj > 0; jj >>= 1) {
          for (int i = lane; i < n2; i += 64) {
            int ixj = i ^ jj;
            if (ixj > i) {
              unsigned long long a = edges[i], c = edges[ixj];
              bool up = ((i & kk) == 0);
              if ((a > c) == up) { edges[i] = c; edges[ixj] = a; }
            }
          }
          __threadfence_block();
        }
      }
    }

    // claim-based parallel Kruskal, exact sequential-order semantics
    int merged = 0;
    const int target = mcnt - 1;
    for (int base = 0; base < ne && merged < target; base += 64) {
      const int idx = base + lane;
      bool unresolved = (idx < ne);
      const unsigned long long e = unresolved ? edges[idx] : 0ULL;
      const int A  = (int)((e >> 10) & 1023u);
      const int Bq = (int)(e & 1023u);
      const float ev = __uint_as_float((unsigned)(e >> 32));
      for (;;) {
        int rA = A, rB = Bq;
        if (unresolved) {
          int xx = A;
          for (;;) { int p1 = parent[xx]; if (p1 == xx) break;
                     int p2 = parent[p1]; parent[xx] = p2; xx = p2; }
          rA = xx;
          xx = Bq;
          for (;;) { int p1 = parent[xx]; if (p1 == xx) break;
                     int p2 = parent[p1]; parent[xx] = p2; xx = p2; }
          rB = xx;
        }
        bool crossing = unresolved && (rA != rB);
        if (unresolved && !crossing) unresolved = false;
        if (__ballot(crossing) == 0ULL) break;
        if (crossing) {
          atomicMin(&claims[rA], (unsigned)lane);
          atomicMin(&claims[rB], (unsigned)lane);
        }
        __threadfence_block();
        bool win = crossing && claims[rA] == (unsigned)lane
                            && claims[rB] == (unsigned)lane;
        __threadfence_block();
        if (crossing) { claims[rA] = 0xFFFFFFFFu; claims[rB] = 0xFFFFFFFFu; }
        if (win) {
          unsigned long long ka = oldkey[rA], kb = oldkey[rB];
          unsigned ra_ = rank_s[rA], rb_ = rank_s[rB];
          int big   = (ra_ > rb_) ? rA : ((rb_ > ra_) ? rB : ((rA < rB) ? rA : rB));
          int small = (big == rA) ? rB : rA;
          parent[small] = big;
          if (ra_ == rb_) rank_s[big] = ra_ + 1u;
          unsigned long long okmin = (ka < kb) ? ka : kb;
          unsigned long long okmax = (ka < kb) ? kb : ka;
          oldkey[big] = okmin;
          int dying = (int)(okmax & 1023u);
          deathv[dying] = ev;
          unresolved = false;
        }
        __threadfence_block();
        merged += (int)__popcll(__ballot(win));
        if (merged >= target) break;
      }
    }
    __threadfence_block();

    // landscape features: top-2 tents over minima per t (lanes 0..24)
    if (lane < TPTS) {
      float ti = (float)((double)lane * (100.0 / 24.0));
      float t1 = 0.f, t2 = 0.f;
      for (int ii = 0; ii < mcnt; ii++) {
        int m = mlist[ii];
        float tent = fminf(ti - val_s[m], deathv[m] - ti);
        tent = fmaxf(tent, 0.f);
        if (tent > t1)      { t2 = t1; t1 = tent; }
        else if (tent > t2) { t2 = tent; }
      }
      feats[b * NFEAT + lane]        = t1;
      feats[b * NFEAT + TPTS + lane] = t2;
    }
  }

  // ---- last block computes the dense head ----
  __threadfence();
  __syncthreads();
  if (tid == 0) last_sh = (atomicAdd(done_ctr, 1) == BATCH - 1) ? 1 : 0;
  __syncthreads();
  if (!last_sh) return;
  __threadfence();

  for (int i = tid; i < BATCH * NFEAT; i += BT2) f_s[i] = feats[i];
  __syncthreads();
  for (int idx = tid; idx < BATCH * OUTF; idx += BT2) {
    int bb = idx / OUTF, ff = idx % OUTF;
    float acc = b_land[ff];
    const float* wr = w_land + ff * NFEAT;
    const float* fr = f_s + bb * NFEAT;
    for (int j = 0; j < NFEAT; j++) acc += fr[j] * wr[j];
    xt_s[idx] = acc;
  }
  __syncthreads();
  if (tid < OUTF) {
    float s = 0.f;
    for (int bb = 0; bb < BATCH; bb++) s += fabsf(xt_s[bb * OUTF + tid]);
    out[BATCH * NCLS + tid] = s;
  }
  for (int idx = tid; idx < BATCH * NCLS; idx += BT2) {
    int bb = idx / NCLS, cc = idx % NCLS;
    float acc = b_fc[cc];
    const float* wr = w_fc + cc * OUTF;
    const float* xr = xt_s + bb * OUTF;
    for (int ff = 0; ff < OUTF; ff++) acc += fmaxf(xr[ff], 0.f) * wr[ff];
    out[bb * NCLS + cc] = acc;
  }
}

// ---------------------------------------------------------------------------
extern "C" void kernel_launch(void* const* d_in, const int* in_sizes, int n_in,
                              void* d_out, int out_size, void* d_ws, size_t ws_size,
                              hipStream_t stream) {
  (void)in_sizes; (void)n_in; (void)out_size; (void)ws_size;
  const float* x      = (const float*)d_in[0];   // [32,1,28,28]
  const float* w_land = (const float*)d_in[1];   // [50,50]
  const float* b_land = (const float*)d_in[2];   // [50]
  const float* w_fc   = (const float*)d_in[3];   // [10,50]
  const float* b_fc   = (const float*)d_in[4];   // [10]
  float* out   = (float*)d_out;                  // [32*10] out then [50] signal
  float* v     = (float*)d_ws;                   // [32*784]
  float* feats = v + BATCH * G784;               // [32*50]
  int*   done  = (int*)(feats + BATCH * NFEAT);  // [1]

  dim3 g1(BATCH, NBX);
  dtm_kernel<<<g1, BT, 0, stream>>>(x, v, done);
  pd0_kernel<<<BATCH, BT2, 0, stream>>>(v, feats, done,
                                        w_land, b_land, w_fc, b_fc, out);
}